// Round 3
// baseline (16005.475 us; speedup 1.0000x reference)
//
#include <hip/hip_runtime.h>
#include <hip/hip_fp16.h>
#include <math.h>

// Problem dims
#define TT 256
#define BB 64
#define DD 512
#define HH 512
#define NC 2048  // 4 gates * H, interleaved col = j*4 + g  (g: 0=i,1=f,2=o,3=ctilde)

// Workspace layout (float offsets).
#define XT_OFF 0ull          // [16384][512]  xt precompute, row = t*64+b
#define DH_OFF 8388608ull    // [16384][512]  delta_h precompute
#define GP_OFF 16777216ull   // [16384][2048] G_pre = XT@Wx + M@Wm + b
#define WX_OFF 50331648ull   // [512][2048] fp32
#define WM_OFF 51380224ull   // [512][2048] fp32
#define WHT_OFF 52428800ull  // [2048][512] f16 (occupies 524288 float slots)
#define BC_OFF 52953088ull   // [2048]

__device__ __forceinline__ float sigmoidf_(float v) { return 1.0f / (1.0f + expf(-v)); }

typedef _Float16 f16x2 __attribute__((ext_vector_type(2)));

__device__ __forceinline__ float dot2acc(unsigned int a, unsigned int b, float acc) {
  f16x2 av = __builtin_bit_cast(f16x2, a);
  f16x2 bv = __builtin_bit_cast(f16x2, b);
#if defined(__has_builtin)
#if __has_builtin(__builtin_amdgcn_fdot2)
  return __builtin_amdgcn_fdot2(av, bv, acc, false);
#else
  acc = fmaf((float)av.x, (float)bv.x, acc);
  return fmaf((float)av.y, (float)bv.y, acc);
#endif
#else
  acc = fmaf((float)av.x, (float)bv.x, acc);
  return fmaf((float)av.y, (float)bv.y, acc);
#endif
}

// ---------------------------------------------------------------------------
// Repack gate weights [1536][512] x4:
//   WX fp32 [512][2048]  (x part, gate-interleaved col = j*4+g)
//   WM fp32 [512][2048]  (m part)
//   WHT f16 [2048][512]  (h part, TRANSPOSED: row = gate col, k-contiguous)
//   BC  [2048]
// ---------------------------------------------------------------------------
__global__ __launch_bounds__(256) void repack_kernel(
    const float* __restrict__ Wi, const float* __restrict__ bi,
    const float* __restrict__ Wf, const float* __restrict__ bff,
    const float* __restrict__ Wo, const float* __restrict__ bo,
    const float* __restrict__ Wc, const float* __restrict__ bc,
    float* __restrict__ WX, __half* __restrict__ WHT, float* __restrict__ WM,
    float* __restrict__ BC) {
  int idx = blockIdx.x * 256 + threadIdx.x;  // 512*512
  int k = idx >> 9, j = idx & 511;
  const float* Ws[4] = {Wi, Wf, Wo, Wc};
  const float* bs[4] = {bi, bff, bo, bc};
#pragma unroll
  for (int g = 0; g < 4; ++g) {
    const float* W = Ws[g];
    WX[(size_t)k * NC + j * 4 + g] = W[(size_t)k * 512 + j];
    WHT[(size_t)(j * 4 + g) * 512 + k] = __float2half(W[(size_t)(512 + k) * 512 + j]);
    WM[(size_t)k * NC + j * 4 + g] = W[(size_t)(1024 + k) * 512 + j];
    if (k == 0) BC[j * 4 + g] = bs[g][j];
  }
}

// ---------------------------------------------------------------------------
// XT[t*64+b][d] = m*X + (1-m)*(dx*Xl + (1-dx)*xm),  dx = exp(-relu(dl*gxw+gxb))
// x layout: [B][4][T][D]; channel 0=X,1=Xl,2=M,3=Dl
// ---------------------------------------------------------------------------
__global__ __launch_bounds__(256) void xt_kernel(
    const float* __restrict__ x, const float* __restrict__ Xmean,
    const float* __restrict__ gxw, const float* __restrict__ gxb,
    float* __restrict__ XT) {
  int idx = blockIdx.x * 256 + threadIdx.x;  // 2,097,152 float4 slots
  int d = (idx & 127) * 4;
  int r = idx >> 7;  // t*64+b
  int b = r & 63, t = r >> 6;
  size_t base = (((size_t)b * 4) * TT + t) * DD + d;
  const float4 X = *(const float4*)&x[base];
  const float4 Xl = *(const float4*)&x[base + (size_t)TT * DD];
  const float4 M = *(const float4*)&x[base + 2ull * TT * DD];
  const float4 Dl = *(const float4*)&x[base + 3ull * TT * DD];
  const float4 xm = *(const float4*)&Xmean[(size_t)t * DD + d];
  const float4 gw = *(const float4*)&gxw[d];
  const float4 gb = *(const float4*)&gxb[d];
  float4 o;
  {
    float dx = expf(-fmaxf(0.f, Dl.x * gw.x + gb.x));
    o.x = M.x * X.x + (1.f - M.x) * (dx * Xl.x + (1.f - dx) * xm.x);
  }
  {
    float dx = expf(-fmaxf(0.f, Dl.y * gw.y + gb.y));
    o.y = M.y * X.y + (1.f - M.y) * (dx * Xl.y + (1.f - dx) * xm.y);
  }
  {
    float dx = expf(-fmaxf(0.f, Dl.z * gw.z + gb.z));
    o.z = M.z * X.z + (1.f - M.z) * (dx * Xl.z + (1.f - dx) * xm.z);
  }
  {
    float dx = expf(-fmaxf(0.f, Dl.w * gw.w + gb.w));
    o.w = M.w * X.w + (1.f - M.w) * (dx * Xl.w + (1.f - dx) * xm.w);
  }
  *(float4*)&XT[(size_t)r * DD + d] = o;
}

// ---------------------------------------------------------------------------
// DH = exp(-relu(Dl @ gh_W + gh_b)) : [16384,512] @ [512,512]
// fp32 tiled GEMM, BM=BN=64, BK=32, 256 threads, 4x4 microtile.
// ---------------------------------------------------------------------------
__global__ __launch_bounds__(256) void gemm_dh(
    const float* __restrict__ x, const float* __restrict__ ghW,
    const float* __restrict__ ghb, float* __restrict__ DH) {
  __shared__ float As[32][68];
  __shared__ float Bs[32][64];
  const int tid = threadIdx.x;
  const int bx = blockIdx.x, by = blockIdx.y;
  const int tx = tid & 15, ty = tid >> 4;
  float acc[4][4] = {};

  const int arow = tid >> 2, akq = (tid & 3) * 8;
  const int rg = by * 64 + arow;
  const int ab = rg & 63, at = rg >> 6;
  const float* Arow = &x[(((size_t)ab * 4 + 3) * TT + at) * DD];
  const int bk = tid >> 3, bcq = (tid & 7) * 8;

  for (int k0 = 0; k0 < 512; k0 += 32) {
    float4 a0 = *(const float4*)&Arow[k0 + akq];
    float4 a1 = *(const float4*)&Arow[k0 + akq + 4];
    float4 b0 = *(const float4*)&ghW[(size_t)(k0 + bk) * 512 + bx * 64 + bcq];
    float4 b1 = *(const float4*)&ghW[(size_t)(k0 + bk) * 512 + bx * 64 + bcq + 4];
    __syncthreads();
    As[akq + 0][arow] = a0.x; As[akq + 1][arow] = a0.y;
    As[akq + 2][arow] = a0.z; As[akq + 3][arow] = a0.w;
    As[akq + 4][arow] = a1.x; As[akq + 5][arow] = a1.y;
    As[akq + 6][arow] = a1.z; As[akq + 7][arow] = a1.w;
    *(float4*)&Bs[bk][bcq] = b0;
    *(float4*)&Bs[bk][bcq + 4] = b1;
    __syncthreads();
#pragma unroll
    for (int kk = 0; kk < 32; ++kk) {
      float4 av = *(const float4*)&As[kk][ty * 4];
      float4 bv = *(const float4*)&Bs[kk][tx * 4];
      acc[0][0] += av.x * bv.x; acc[0][1] += av.x * bv.y; acc[0][2] += av.x * bv.z; acc[0][3] += av.x * bv.w;
      acc[1][0] += av.y * bv.x; acc[1][1] += av.y * bv.y; acc[1][2] += av.y * bv.z; acc[1][3] += av.y * bv.w;
      acc[2][0] += av.z * bv.x; acc[2][1] += av.z * bv.y; acc[2][2] += av.z * bv.z; acc[2][3] += av.z * bv.w;
      acc[3][0] += av.w * bv.x; acc[3][1] += av.w * bv.y; acc[3][2] += av.w * bv.z; acc[3][3] += av.w * bv.w;
    }
  }
  const int col0 = bx * 64 + tx * 4;
  const int row0 = by * 64 + ty * 4;
#pragma unroll
  for (int i = 0; i < 4; ++i) {
    float4 v;
    v.x = expf(-fmaxf(0.f, acc[i][0] + ghb[col0 + 0]));
    v.y = expf(-fmaxf(0.f, acc[i][1] + ghb[col0 + 1]));
    v.z = expf(-fmaxf(0.f, acc[i][2] + ghb[col0 + 2]));
    v.w = expf(-fmaxf(0.f, acc[i][3] + ghb[col0 + 3]));
    *(float4*)&DH[(size_t)(row0 + i) * 512 + col0] = v;
  }
}

// ---------------------------------------------------------------------------
// G_pre = XT @ WX + M @ WM + BC : [16384,2048], two K=512 passes.
// ---------------------------------------------------------------------------
__global__ __launch_bounds__(256) void gemm_gp(
    const float* __restrict__ x, const float* __restrict__ XT,
    const float* __restrict__ WX, const float* __restrict__ WM,
    const float* __restrict__ BC, float* __restrict__ GP) {
  __shared__ float As[32][68];
  __shared__ float Bs[32][64];
  const int tid = threadIdx.x;
  const int bx = blockIdx.x, by = blockIdx.y;
  const int tx = tid & 15, ty = tid >> 4;
  float acc[4][4] = {};

  const int arow = tid >> 2, akq = (tid & 3) * 8;
  const int rg = by * 64 + arow;
  const int ab = rg & 63, at = rg >> 6;
  const int bk = tid >> 3, bcq = (tid & 7) * 8;

  for (int s = 0; s < 2; ++s) {
    const float* B = s ? WM : WX;
    const float* Arow = s ? &x[(((size_t)ab * 4 + 2) * TT + at) * DD]
                          : &XT[(size_t)rg * DD];
    for (int k0 = 0; k0 < 512; k0 += 32) {
      float4 a0 = *(const float4*)&Arow[k0 + akq];
      float4 a1 = *(const float4*)&Arow[k0 + akq + 4];
      float4 b0 = *(const float4*)&B[(size_t)(k0 + bk) * NC + bx * 64 + bcq];
      float4 b1 = *(const float4*)&B[(size_t)(k0 + bk) * NC + bx * 64 + bcq + 4];
      __syncthreads();
      As[akq + 0][arow] = a0.x; As[akq + 1][arow] = a0.y;
      As[akq + 2][arow] = a0.z; As[akq + 3][arow] = a0.w;
      As[akq + 4][arow] = a1.x; As[akq + 5][arow] = a1.y;
      As[akq + 6][arow] = a1.z; As[akq + 7][arow] = a1.w;
      *(float4*)&Bs[bk][bcq] = b0;
      *(float4*)&Bs[bk][bcq + 4] = b1;
      __syncthreads();
#pragma unroll
      for (int kk = 0; kk < 32; ++kk) {
        float4 av = *(const float4*)&As[kk][ty * 4];
        float4 bv = *(const float4*)&Bs[kk][tx * 4];
        acc[0][0] += av.x * bv.x; acc[0][1] += av.x * bv.y; acc[0][2] += av.x * bv.z; acc[0][3] += av.x * bv.w;
        acc[1][0] += av.y * bv.x; acc[1][1] += av.y * bv.y; acc[1][2] += av.y * bv.z; acc[1][3] += av.y * bv.w;
        acc[2][0] += av.z * bv.x; acc[2][1] += av.z * bv.y; acc[2][2] += av.z * bv.z; acc[2][3] += av.z * bv.w;
        acc[3][0] += av.w * bv.x; acc[3][1] += av.w * bv.y; acc[3][2] += av.w * bv.z; acc[3][3] += av.w * bv.w;
      }
    }
  }
  const int col0 = bx * 64 + tx * 4;
  const int row0 = by * 64 + ty * 4;
  const float4 bc4 = *(const float4*)&BC[col0];
#pragma unroll
  for (int i = 0; i < 4; ++i) {
    float4 v;
    v.x = acc[i][0] + bc4.x;
    v.y = acc[i][1] + bc4.y;
    v.z = acc[i][2] + bc4.z;
    v.w = acc[i][3] + bc4.w;
    *(float4*)&GP[(size_t)(row0 + i) * NC + col0] = v;
  }
}

// ---------------------------------------------------------------------------
// Per-batch-row recurrence: 64 blocks x 1024 threads, ZERO grid syncs.
// Block b owns batch row b; h/c state never leave the block.
//   - Thread i owns gate cols {2i, 2i+1}. With col = 4j+g interleave, the
//     pair (2j, 2j+1) of adjacent lanes covers the 4 gates of hidden unit j:
//     even thread -> (i,f), odd thread -> (o,ctilde). Exchange via shfl_xor.
//   - WHT f16 [col][k] streamed from L2 (dwordx4), dot via v_dot2_f32_f16.
//   - hscaled (= DH[t]*h) f16 in LDS, read with wave-uniform addresses
//     (same-address broadcast = conflict-free). One __syncthreads per step.
//   - c-state in even-lane registers.
// ---------------------------------------------------------------------------
__global__ __launch_bounds__(1024) void persist_rnn(
    const float* __restrict__ GP, const float* __restrict__ DH,
    const __half* __restrict__ WHT, float* __restrict__ out) {
  __shared__ __align__(16) __half hsl[2][512];
  const int b = blockIdx.x;
  const int tid = threadIdx.x;  // 0..1023
  const int j = tid >> 1;       // hidden unit for this pair
  const int c0 = tid * 2;       // first owned gate col

  if (tid < 512) hsl[0][tid] = __float2half(0.f);
  __syncthreads();

  const __half* w0 = WHT + (size_t)c0 * 512;
  const __half* w1 = w0 + 512;
  float cstate = 0.f;

  for (int t = 0; t < TT; ++t) {
    const int cur = t & 1;
    const float2 gp = *(const float2*)&GP[((size_t)t * 64 + b) * NC + c0];
    float acc0 = 0.f, acc1 = 0.f;
#pragma unroll 4
    for (int k = 0; k < 512; k += 8) {
      uint4 hv = *(const uint4*)&hsl[cur][k];   // wave-uniform -> broadcast
      uint4 wa = *(const uint4*)&w0[k];
      uint4 wb = *(const uint4*)&w1[k];
      acc0 = dot2acc(hv.x, wa.x, acc0);
      acc0 = dot2acc(hv.y, wa.y, acc0);
      acc0 = dot2acc(hv.z, wa.z, acc0);
      acc0 = dot2acc(hv.w, wa.w, acc0);
      acc1 = dot2acc(hv.x, wb.x, acc1);
      acc1 = dot2acc(hv.y, wb.y, acc1);
      acc1 = dot2acc(hv.z, wb.z, acc1);
      acc1 = dot2acc(hv.w, wb.w, acc1);
    }
    acc0 += gp.x;
    acc1 += gp.y;
    // even lane: acc0=i_pre, acc1=f_pre ; odd lane: acc0=o_pre, acc1=ct_pre
    float sg0 = sigmoidf_(acc0);
    float v1 = (tid & 1) ? tanhf(acc1) : sigmoidf_(acc1);
    float p0 = __shfl_xor(sg0, 1);  // partner's sigmoid
    float p1 = __shfl_xor(v1, 1);   // partner's second value
    if (!(tid & 1)) {
      // ig=sg0, fg=v1, og=p0, ct=p1
      cstate = v1 * cstate + sg0 * p1;
      float h = p0 * tanhf(cstate);
      out[((size_t)b * TT + t) * HH + j] = h;
      if (t + 1 < TT) {
        float d = DH[((size_t)(t + 1) * 64 + b) * HH + j];
        hsl[cur ^ 1][j] = __float2half(d * h);
      }
    }
    __syncthreads();
  }
}

// ---------------------------------------------------------------------------
extern "C" void kernel_launch(void* const* d_in, const int* in_sizes, int n_in,
                              void* d_out, int out_size, void* d_ws,
                              size_t ws_size, hipStream_t stream) {
  const float* x = (const float*)d_in[0];
  const float* Xmean = (const float*)d_in[1];
  const float* Wi = (const float*)d_in[2];
  const float* bi = (const float*)d_in[3];
  const float* Wf = (const float*)d_in[4];
  const float* bf = (const float*)d_in[5];
  const float* Wo = (const float*)d_in[6];
  const float* bo = (const float*)d_in[7];
  const float* Wc = (const float*)d_in[8];
  const float* bc = (const float*)d_in[9];
  const float* gxw = (const float*)d_in[10];
  const float* gxb = (const float*)d_in[11];
  const float* ghW = (const float*)d_in[12];
  const float* ghb = (const float*)d_in[13];
  float* out = (float*)d_out;
  float* ws = (float*)d_ws;

  float* XT = ws + XT_OFF;
  float* DH = ws + DH_OFF;
  float* GP = ws + GP_OFF;
  float* WX = ws + WX_OFF;
  float* WM = ws + WM_OFF;
  __half* WHT = (__half*)(ws + WHT_OFF);
  float* BC = ws + BC_OFF;

  repack_kernel<<<1024, 256, 0, stream>>>(Wi, bi, Wf, bf, Wo, bo, Wc, bc,
                                          WX, WHT, WM, BC);
  xt_kernel<<<8192, 256, 0, stream>>>(x, Xmean, gxw, gxb, XT);
  gemm_dh<<<dim3(8, 256), 256, 0, stream>>>(x, ghW, ghb, DH);
  gemm_gp<<<dim3(32, 256), 256, 0, stream>>>(x, XT, WX, WM, BC, GP);

  persist_rnn<<<64, 1024, 0, stream>>>(GP, DH, WHT, out);
}

// Round 4
// 2664.145 us; speedup vs baseline: 6.0077x; 6.0077x over previous
//
#include <hip/hip_runtime.h>
#include <hip/hip_fp16.h>
#include <math.h>

// Problem dims
#define TT 256
#define BB 64
#define DD 512
#define HH 512
#define NC 2048  // 4 gates * H, interleaved col = j*4 + g  (g: 0=i,1=f,2=o,3=ctilde)

// Workspace layout (float offsets).
#define XT_OFF 0ull          // [16384][512]  xt precompute, row = t*64+b
#define DH_OFF 8388608ull    // [16384][512]  delta_h precompute
#define GP_OFF 16777216ull   // [16384][2048] G_pre = XT@Wx + M@Wm + b
#define WX_OFF 50331648ull   // [512][2048] fp32
#define WM_OFF 51380224ull   // [512][2048] fp32
#define WHT_OFF 52428800ull  // [2048][512] f16 (524288 float slots)
#define BC_OFF 52953088ull   // [2048]
#define HS_OFF 52955136ull   // hs[2][64][256] uint (f16 pairs) = 32768 float slots
#define BAR_OFF 52987904ull  // int bar[16]

__device__ __forceinline__ float sigmoidf_(float v) { return 1.0f / (1.0f + expf(-v)); }

typedef _Float16 half8 __attribute__((ext_vector_type(8)));
typedef float f32x4 __attribute__((ext_vector_type(4)));

// ---------------------------------------------------------------------------
// Repack gate weights [1536][512] x4:
//   WX fp32 [512][2048]  (x part, gate-interleaved col = j*4+g)
//   WM fp32 [512][2048]  (m part)
//   WHT f16 [2048][512]  (h part, TRANSPOSED: row = gate col, k-contiguous)
//   BC  [2048]
// ---------------------------------------------------------------------------
__global__ __launch_bounds__(256) void repack_kernel(
    const float* __restrict__ Wi, const float* __restrict__ bi,
    const float* __restrict__ Wf, const float* __restrict__ bff,
    const float* __restrict__ Wo, const float* __restrict__ bo,
    const float* __restrict__ Wc, const float* __restrict__ bc,
    float* __restrict__ WX, __half* __restrict__ WHT, float* __restrict__ WM,
    float* __restrict__ BC) {
  int idx = blockIdx.x * 256 + threadIdx.x;  // 512*512
  int k = idx >> 9, j = idx & 511;
  const float* Ws[4] = {Wi, Wf, Wo, Wc};
  const float* bs[4] = {bi, bff, bo, bc};
#pragma unroll
  for (int g = 0; g < 4; ++g) {
    const float* W = Ws[g];
    WX[(size_t)k * NC + j * 4 + g] = W[(size_t)k * 512 + j];
    WHT[(size_t)(j * 4 + g) * 512 + k] = __float2half(W[(size_t)(512 + k) * 512 + j]);
    WM[(size_t)k * NC + j * 4 + g] = W[(size_t)(1024 + k) * 512 + j];
    if (k == 0) BC[j * 4 + g] = bs[g][j];
  }
}

// ---------------------------------------------------------------------------
// XT[t*64+b][d] = m*X + (1-m)*(dx*Xl + (1-dx)*xm),  dx = exp(-relu(dl*gxw+gxb))
// ---------------------------------------------------------------------------
__global__ __launch_bounds__(256) void xt_kernel(
    const float* __restrict__ x, const float* __restrict__ Xmean,
    const float* __restrict__ gxw, const float* __restrict__ gxb,
    float* __restrict__ XT) {
  int idx = blockIdx.x * 256 + threadIdx.x;
  int d = (idx & 127) * 4;
  int r = idx >> 7;  // t*64+b
  int b = r & 63, t = r >> 6;
  size_t base = (((size_t)b * 4) * TT + t) * DD + d;
  const float4 X = *(const float4*)&x[base];
  const float4 Xl = *(const float4*)&x[base + (size_t)TT * DD];
  const float4 M = *(const float4*)&x[base + 2ull * TT * DD];
  const float4 Dl = *(const float4*)&x[base + 3ull * TT * DD];
  const float4 xm = *(const float4*)&Xmean[(size_t)t * DD + d];
  const float4 gw = *(const float4*)&gxw[d];
  const float4 gb = *(const float4*)&gxb[d];
  float4 o;
  {
    float dx = expf(-fmaxf(0.f, Dl.x * gw.x + gb.x));
    o.x = M.x * X.x + (1.f - M.x) * (dx * Xl.x + (1.f - dx) * xm.x);
  }
  {
    float dx = expf(-fmaxf(0.f, Dl.y * gw.y + gb.y));
    o.y = M.y * X.y + (1.f - M.y) * (dx * Xl.y + (1.f - dx) * xm.y);
  }
  {
    float dx = expf(-fmaxf(0.f, Dl.z * gw.z + gb.z));
    o.z = M.z * X.z + (1.f - M.z) * (dx * Xl.z + (1.f - dx) * xm.z);
  }
  {
    float dx = expf(-fmaxf(0.f, Dl.w * gw.w + gb.w));
    o.w = M.w * X.w + (1.f - M.w) * (dx * Xl.w + (1.f - dx) * xm.w);
  }
  *(float4*)&XT[(size_t)r * DD + d] = o;
}

// ---------------------------------------------------------------------------
// DH = exp(-relu(Dl @ gh_W + gh_b)) : [16384,512] @ [512,512]  (fp32 tiled)
// ---------------------------------------------------------------------------
__global__ __launch_bounds__(256) void gemm_dh(
    const float* __restrict__ x, const float* __restrict__ ghW,
    const float* __restrict__ ghb, float* __restrict__ DH) {
  __shared__ float As[32][68];
  __shared__ float Bs[32][64];
  const int tid = threadIdx.x;
  const int bx = blockIdx.x, by = blockIdx.y;
  const int tx = tid & 15, ty = tid >> 4;
  float acc[4][4] = {};

  const int arow = tid >> 2, akq = (tid & 3) * 8;
  const int rg = by * 64 + arow;
  const int ab = rg & 63, at = rg >> 6;
  const float* Arow = &x[(((size_t)ab * 4 + 3) * TT + at) * DD];
  const int bk = tid >> 3, bcq = (tid & 7) * 8;

  for (int k0 = 0; k0 < 512; k0 += 32) {
    float4 a0 = *(const float4*)&Arow[k0 + akq];
    float4 a1 = *(const float4*)&Arow[k0 + akq + 4];
    float4 b0 = *(const float4*)&ghW[(size_t)(k0 + bk) * 512 + bx * 64 + bcq];
    float4 b1 = *(const float4*)&ghW[(size_t)(k0 + bk) * 512 + bx * 64 + bcq + 4];
    __syncthreads();
    As[akq + 0][arow] = a0.x; As[akq + 1][arow] = a0.y;
    As[akq + 2][arow] = a0.z; As[akq + 3][arow] = a0.w;
    As[akq + 4][arow] = a1.x; As[akq + 5][arow] = a1.y;
    As[akq + 6][arow] = a1.z; As[akq + 7][arow] = a1.w;
    *(float4*)&Bs[bk][bcq] = b0;
    *(float4*)&Bs[bk][bcq + 4] = b1;
    __syncthreads();
#pragma unroll
    for (int kk = 0; kk < 32; ++kk) {
      float4 av = *(const float4*)&As[kk][ty * 4];
      float4 bv = *(const float4*)&Bs[kk][tx * 4];
      acc[0][0] += av.x * bv.x; acc[0][1] += av.x * bv.y; acc[0][2] += av.x * bv.z; acc[0][3] += av.x * bv.w;
      acc[1][0] += av.y * bv.x; acc[1][1] += av.y * bv.y; acc[1][2] += av.y * bv.z; acc[1][3] += av.y * bv.w;
      acc[2][0] += av.z * bv.x; acc[2][1] += av.z * bv.y; acc[2][2] += av.z * bv.z; acc[2][3] += av.z * bv.w;
      acc[3][0] += av.w * bv.x; acc[3][1] += av.w * bv.y; acc[3][2] += av.w * bv.z; acc[3][3] += av.w * bv.w;
    }
  }
  const int col0 = bx * 64 + tx * 4;
  const int row0 = by * 64 + ty * 4;
#pragma unroll
  for (int i = 0; i < 4; ++i) {
    float4 v;
    v.x = expf(-fmaxf(0.f, acc[i][0] + ghb[col0 + 0]));
    v.y = expf(-fmaxf(0.f, acc[i][1] + ghb[col0 + 1]));
    v.z = expf(-fmaxf(0.f, acc[i][2] + ghb[col0 + 2]));
    v.w = expf(-fmaxf(0.f, acc[i][3] + ghb[col0 + 3]));
    *(float4*)&DH[(size_t)(row0 + i) * 512 + col0] = v;
  }
}

// ---------------------------------------------------------------------------
// G_pre = XT @ WX + M @ WM + BC : [16384,2048], two K=512 passes. (fp32 tiled)
// ---------------------------------------------------------------------------
__global__ __launch_bounds__(256) void gemm_gp(
    const float* __restrict__ x, const float* __restrict__ XT,
    const float* __restrict__ WX, const float* __restrict__ WM,
    const float* __restrict__ BC, float* __restrict__ GP) {
  __shared__ float As[32][68];
  __shared__ float Bs[32][64];
  const int tid = threadIdx.x;
  const int bx = blockIdx.x, by = blockIdx.y;
  const int tx = tid & 15, ty = tid >> 4;
  float acc[4][4] = {};

  const int arow = tid >> 2, akq = (tid & 3) * 8;
  const int rg = by * 64 + arow;
  const int ab = rg & 63, at = rg >> 6;
  const int bk = tid >> 3, bcq = (tid & 7) * 8;

  for (int s = 0; s < 2; ++s) {
    const float* B = s ? WM : WX;
    const float* Arow = s ? &x[(((size_t)ab * 4 + 2) * TT + at) * DD]
                          : &XT[(size_t)rg * DD];
    for (int k0 = 0; k0 < 512; k0 += 32) {
      float4 a0 = *(const float4*)&Arow[k0 + akq];
      float4 a1 = *(const float4*)&Arow[k0 + akq + 4];
      float4 b0 = *(const float4*)&B[(size_t)(k0 + bk) * NC + bx * 64 + bcq];
      float4 b1 = *(const float4*)&B[(size_t)(k0 + bk) * NC + bx * 64 + bcq + 4];
      __syncthreads();
      As[akq + 0][arow] = a0.x; As[akq + 1][arow] = a0.y;
      As[akq + 2][arow] = a0.z; As[akq + 3][arow] = a0.w;
      As[akq + 4][arow] = a1.x; As[akq + 5][arow] = a1.y;
      As[akq + 6][arow] = a1.z; As[akq + 7][arow] = a1.w;
      *(float4*)&Bs[bk][bcq] = b0;
      *(float4*)&Bs[bk][bcq + 4] = b1;
      __syncthreads();
#pragma unroll
      for (int kk = 0; kk < 32; ++kk) {
        float4 av = *(const float4*)&As[kk][ty * 4];
        float4 bv = *(const float4*)&Bs[kk][tx * 4];
        acc[0][0] += av.x * bv.x; acc[0][1] += av.x * bv.y; acc[0][2] += av.x * bv.z; acc[0][3] += av.x * bv.w;
        acc[1][0] += av.y * bv.x; acc[1][1] += av.y * bv.y; acc[1][2] += av.y * bv.z; acc[1][3] += av.y * bv.w;
        acc[2][0] += av.z * bv.x; acc[2][1] += av.z * bv.y; acc[2][2] += av.z * bv.z; acc[2][3] += av.z * bv.w;
        acc[3][0] += av.w * bv.x; acc[3][1] += av.w * bv.y; acc[3][2] += av.w * bv.z; acc[3][3] += av.w * bv.w;
      }
    }
  }
  const int col0 = bx * 64 + tx * 4;
  const int row0 = by * 64 + ty * 4;
  const float4 bc4 = *(const float4*)&BC[col0];
#pragma unroll
  for (int i = 0; i < 4; ++i) {
    float4 v;
    v.x = acc[i][0] + bc4.x;
    v.y = acc[i][1] + bc4.y;
    v.z = acc[i][2] + bc4.z;
    v.w = acc[i][3] + bc4.w;
    *(float4*)&GP[(size_t)(row0 + i) * NC + col0] = v;
  }
}

// ---------------------------------------------------------------------------
// Recurrence: 32 blocks x 512 threads, cooperative. 4 groups of 8 blocks.
// Group g owns batch rows [16g, 16g+16); member m owns gate cols
// [256m, 256m+256) = hidden units [64m, 64m+64).
//   - WH held ENTIRELY IN REGISTERS as MFMA B-fragments (loaded once):
//     wave w holds cols [256m+32w, +32) = 2 N-tiles x 16 K-tiles = 128 VGPRs.
//   - Per step: h-scaled (16 rows x 512 f16) loaded agent-scope from L3 into
//     LDS, MFMA [16x512]@[512x256] per block, epilogue adds GP, activations,
//     c-state in registers, h-scaled written agent-scope, 8-block barrier
//     (monotone counter, release/acquire agent atomics).
//   - fragment layouts (m89/m120): A[m=lane&15][k=quad*8+j],
//     B[n=lane&15][k=quad*8+j], D col=lane&15, row=quad*4+reg.
// ---------------------------------------------------------------------------
__global__ __launch_bounds__(512, 2) void persist_rnn(
    const float* __restrict__ GP, const float* __restrict__ DH,
    const __half* __restrict__ WHT, unsigned* __restrict__ hs,
    int* __restrict__ bar, float* __restrict__ out) {
  __shared__ __align__(16) _Float16 hstage[16 * 520];
  __shared__ __align__(16) float gbuf[16 * 260];
  const int g = blockIdx.x & 3;   // group
  const int m = blockIdx.x >> 2;  // member 0..7
  const int tid = threadIdx.x;
  const int lane = tid & 63;
  const int w = tid >> 6;  // wave 0..7
  const int l15 = lane & 15;
  const int quad = lane >> 4;
  const int rowg0 = g << 4;

  // ---- load B fragments (once) ----
  half8 bfrag[2][16];
  const int colbase = (m << 8) + (w << 5);
#pragma unroll
  for (int nt = 0; nt < 2; ++nt) {
#pragma unroll
    for (int kt = 0; kt < 16; ++kt) {
      int col = colbase + nt * 16 + l15;
      int k = kt * 32 + quad * 8;
      bfrag[nt][kt] = *(const half8*)&WHT[(size_t)col * 512 + k];
    }
  }

  float c0 = 0.f, c1 = 0.f;  // c-state for rows (w, w+8), unit ug
  const int r_ep = w;
  const int ug = (m << 6) + lane;  // global unit for epilogue

  for (int t = 0; t < TT; ++t) {
    // prefetch GP (and DH for t+1) for the epilogue
    const float4 gpa =
        *(const float4*)&GP[((size_t)t * 64 + rowg0 + r_ep) * NC + (ug << 2)];
    const float4 gpb =
        *(const float4*)&GP[((size_t)t * 64 + rowg0 + r_ep + 8) * NC + (ug << 2)];
    const int tn = (t + 1 < TT) ? t + 1 : t;
    const float dha = DH[((size_t)tn * 64 + rowg0 + r_ep) * HH + ug];
    const float dhb = DH[((size_t)tn * 64 + rowg0 + r_ep + 8) * HH + ug];

    // ---- stage h-scaled into LDS (agent-scope loads: L3-coherent) ----
    const unsigned* hsp = hs + (size_t)(t & 1) * (64 * 256);
#pragma unroll
    for (int q = 0; q < 8; ++q) {
      int idx = tid + q * 512;  // 0..4095
      int row = idx >> 8;       // 0..15
      int pu = idx & 255;       // f16-pair index
      unsigned v = __hip_atomic_load(&hsp[(size_t)(rowg0 + row) * 256 + pu],
                                     __ATOMIC_RELAXED, __HIP_MEMORY_SCOPE_AGENT);
      *(unsigned*)&hstage[row * 520 + pu * 2] = v;
    }
    __syncthreads();

    // ---- MFMA: gates[16 x 32w..32w+32] += hstage @ WH ----
    f32x4 acc0 = {0.f, 0.f, 0.f, 0.f};
    f32x4 acc1 = {0.f, 0.f, 0.f, 0.f};
    half8 afrag[16];
#pragma unroll
    for (int kt = 0; kt < 16; ++kt)
      afrag[kt] = *(const half8*)&hstage[l15 * 520 + kt * 32 + quad * 8];
#pragma unroll
    for (int kt = 0; kt < 16; ++kt) {
      acc0 = __builtin_amdgcn_mfma_f32_16x16x32_f16(afrag[kt], bfrag[0][kt], acc0, 0, 0, 0);
      acc1 = __builtin_amdgcn_mfma_f32_16x16x32_f16(afrag[kt], bfrag[1][kt], acc1, 0, 0, 0);
    }
#pragma unroll
    for (int reg = 0; reg < 4; ++reg) {
      int row = quad * 4 + reg;
      gbuf[row * 260 + (w << 5) + l15] = acc0[reg];
      gbuf[row * 260 + (w << 5) + 16 + l15] = acc1[reg];
    }
    __syncthreads();

    // ---- epilogue: rows r_ep and r_ep+8, unit ug ----
    unsigned* hsn = hs + (size_t)((t + 1) & 1) * (64 * 256);
    {
      const float4 gv = *(const float4*)&gbuf[r_ep * 260 + (lane << 2) + ((m & 0) )];
      // (lane<<2) spans 0..252 within this block's 256 local cols
      float ig = sigmoidf_(gv.x + gpa.x);
      float fg = sigmoidf_(gv.y + gpa.y);
      float og = sigmoidf_(gv.z + gpa.z);
      float ct = tanhf(gv.w + gpa.w);
      c0 = fg * c0 + ig * ct;
      float h = og * tanhf(c0);
      out[((size_t)(rowg0 + r_ep) * TT + t) * HH + ug] = h;
      if (t + 1 < TT) {
        unsigned short hb = __half_as_ushort(__float2half(dha * h));
        unsigned other = (unsigned)__shfl_xor((int)(unsigned)hb, 1) & 0xffffu;
        if (!(lane & 1)) {
          unsigned word = (unsigned)hb | (other << 16);
          __hip_atomic_store(&hsn[(size_t)(rowg0 + r_ep) * 256 + (ug >> 1)], word,
                             __ATOMIC_RELAXED, __HIP_MEMORY_SCOPE_AGENT);
        }
      }
    }
    {
      const int r2 = r_ep + 8;
      const float4 gv = *(const float4*)&gbuf[r2 * 260 + (lane << 2)];
      float ig = sigmoidf_(gv.x + gpb.x);
      float fg = sigmoidf_(gv.y + gpb.y);
      float og = sigmoidf_(gv.z + gpb.z);
      float ct = tanhf(gv.w + gpb.w);
      c1 = fg * c1 + ig * ct;
      float h = og * tanhf(c1);
      out[((size_t)(rowg0 + r2) * TT + t) * HH + ug] = h;
      if (t + 1 < TT) {
        unsigned short hb = __half_as_ushort(__float2half(dhb * h));
        unsigned other = (unsigned)__shfl_xor((int)(unsigned)hb, 1) & 0xffffu;
        if (!(lane & 1)) {
          unsigned word = (unsigned)hb | (other << 16);
          __hip_atomic_store(&hsn[(size_t)(rowg0 + r2) * 256 + (ug >> 1)], word,
                             __ATOMIC_RELAXED, __HIP_MEMORY_SCOPE_AGENT);
        }
      }
    }

    // ---- group barrier (skip after last step) ----
    __syncthreads();  // drains each wave's vmcnt -> h stores are in L3
    if (t + 1 < TT) {
      if (tid == 0) {
        __hip_atomic_fetch_add(&bar[g], 1, __ATOMIC_RELEASE,
                               __HIP_MEMORY_SCOPE_AGENT);
        const int target = 8 * (t + 1);
        while (__hip_atomic_load(&bar[g], __ATOMIC_ACQUIRE,
                                 __HIP_MEMORY_SCOPE_AGENT) < target) {
          __builtin_amdgcn_s_sleep(2);
        }
      }
      __syncthreads();
    }
  }
}

// ---------------------------------------------------------------------------
extern "C" void kernel_launch(void* const* d_in, const int* in_sizes, int n_in,
                              void* d_out, int out_size, void* d_ws,
                              size_t ws_size, hipStream_t stream) {
  const float* x = (const float*)d_in[0];
  const float* Xmean = (const float*)d_in[1];
  const float* Wi = (const float*)d_in[2];
  const float* bi = (const float*)d_in[3];
  const float* Wf = (const float*)d_in[4];
  const float* bf = (const float*)d_in[5];
  const float* Wo = (const float*)d_in[6];
  const float* bo = (const float*)d_in[7];
  const float* Wc = (const float*)d_in[8];
  const float* bc = (const float*)d_in[9];
  const float* gxw = (const float*)d_in[10];
  const float* gxb = (const float*)d_in[11];
  const float* ghW = (const float*)d_in[12];
  const float* ghb = (const float*)d_in[13];
  float* out = (float*)d_out;
  float* ws = (float*)d_ws;

  float* XT = ws + XT_OFF;
  float* DH = ws + DH_OFF;
  float* GP = ws + GP_OFF;
  float* WX = ws + WX_OFF;
  float* WM = ws + WM_OFF;
  __half* WHT = (__half*)(ws + WHT_OFF);
  float* BC = ws + BC_OFF;
  unsigned* HS = (unsigned*)(ws + HS_OFF);  // [2][64][256] f16-pairs
  int* BAR = (int*)(ws + BAR_OFF);

  // zero hs double buffer + barrier counters (ws poisoned 0xAA each launch)
  hipMemsetAsync(HS, 0, (2ull * 64 * 256 + 16) * sizeof(unsigned), stream);

  repack_kernel<<<1024, 256, 0, stream>>>(Wi, bi, Wf, bf, Wo, bo, Wc, bc,
                                          WX, WHT, WM, BC);
  xt_kernel<<<8192, 256, 0, stream>>>(x, Xmean, gxw, gxb, XT);
  gemm_dh<<<dim3(8, 256), 256, 0, stream>>>(x, ghW, ghb, DH);
  gemm_gp<<<dim3(32, 256), 256, 0, stream>>>(x, XT, WX, WM, BC, GP);

  void* args[] = {(void*)&GP, (void*)&DH, (void*)&WHT,
                  (void*)&HS, (void*)&BAR, (void*)&out};
  hipLaunchCooperativeKernel((const void*)persist_rnn, dim3(32), dim3(512),
                             args, 0, stream);
}

// Round 5
// 1731.846 us; speedup vs baseline: 9.2419x; 1.5383x over previous
//
#include <hip/hip_runtime.h>
#include <hip/hip_fp16.h>
#include <math.h>

// Problem dims
#define TT 256
#define BB 64
#define DD 512
#define HH 512
#define NC 2048  // 4 gates * H, col = j*4+g (g: 0=i,1=f,2=o,3=ctilde)

// Workspace layout (float-slot offsets). Total ~158 MB.
#define AH_OFF   0ull          // f16 [16384][1024]  (xt | m), row = t*64+b
#define DLH_OFF  8388608ull    // f16 [16384][512]   Dl
#define DH_OFF   12582912ull   // f32 [16384][512]   delta_h
#define GP_OFF   20971520ull   // f16 [16384][2048]  G_pre
#define WCT_OFF  37748736ull   // f16 [2048][1024]   gate W (x|m), col-major rows
#define GHT_OFF  38797312ull   // f16 [512][512]     gh_W transposed
#define WHT_OFF  38928384ull   // f16 [2048][512]    gate W h-part, col-major rows
#define BC_OFF   39452672ull   // f32 [2048]
#define HS_OFF   39454720ull   // uint [2][64][256] f16-pair h exchange
#define FLG_OFF  39487488ull   // int [32*32] flags (128B strided)

__device__ __forceinline__ float sigmoidf_(float v) { return 1.0f / (1.0f + expf(-v)); }

typedef _Float16 h8_t __attribute__((ext_vector_type(8)));
typedef _Float16 h4_t __attribute__((ext_vector_type(4)));
typedef float f32x4 __attribute__((ext_vector_type(4)));

// ---------------------------------------------------------------------------
// Repack:
//   WCT f16 [2048][1024]: WCT[4j+g][k<512]=Wg[k][j] (x), [512+k]=Wg[1024+k][j] (m)
//   WHT f16 [2048][512] :  WHT[4j+g][k] = Wg[512+k][j]
//   GHT f16 [512][512]  :  GHT[j][k] = ghW[k][j]
//   BC  f32 [2048]
// ---------------------------------------------------------------------------
__global__ __launch_bounds__(256) void repack_kernel(
    const float* __restrict__ Wi, const float* __restrict__ bi,
    const float* __restrict__ Wf, const float* __restrict__ bff,
    const float* __restrict__ Wo, const float* __restrict__ bo,
    const float* __restrict__ Wc, const float* __restrict__ bc,
    const float* __restrict__ ghW,
    __half* __restrict__ WCT, __half* __restrict__ WHT,
    __half* __restrict__ GHT, float* __restrict__ BC) {
  int idx = blockIdx.x * 256 + threadIdx.x;  // 512*512
  int k = idx >> 9, j = idx & 511;
  const float* Ws[4] = {Wi, Wf, Wo, Wc};
  const float* bs[4] = {bi, bff, bo, bc};
#pragma unroll
  for (int g = 0; g < 4; ++g) {
    const float* W = Ws[g];
    int col = j * 4 + g;
    WCT[(size_t)col * 1024 + k] = __float2half(W[(size_t)k * 512 + j]);
    WCT[(size_t)col * 1024 + 512 + k] = __float2half(W[(size_t)(1024 + k) * 512 + j]);
    WHT[(size_t)col * 512 + k] = __float2half(W[(size_t)(512 + k) * 512 + j]);
    if (k == 0) BC[col] = bs[g][j];
  }
  GHT[(size_t)j * 512 + k] = __float2half(ghW[(size_t)k * 512 + j]);
}

// ---------------------------------------------------------------------------
// xt: AH[r][d] = xt (f16), AH[r][512+d] = m (f16), DLh[r][d] = dl (f16)
// x layout: [B][4][T][D]; 0=X,1=Xl,2=M,3=Dl ; r = t*64+b
// ---------------------------------------------------------------------------
__global__ __launch_bounds__(256) void xt_kernel(
    const float* __restrict__ x, const float* __restrict__ Xmean,
    const float* __restrict__ gxw, const float* __restrict__ gxb,
    __half* __restrict__ AH, __half* __restrict__ DLh) {
  int idx = blockIdx.x * 256 + threadIdx.x;
  int d = (idx & 127) * 4;
  int r = idx >> 7;
  int b = r & 63, t = r >> 6;
  size_t base = (((size_t)b * 4) * TT + t) * DD + d;
  const float4 X = *(const float4*)&x[base];
  const float4 Xl = *(const float4*)&x[base + (size_t)TT * DD];
  const float4 M = *(const float4*)&x[base + 2ull * TT * DD];
  const float4 Dl = *(const float4*)&x[base + 3ull * TT * DD];
  const float4 xm = *(const float4*)&Xmean[(size_t)t * DD + d];
  const float4 gw = *(const float4*)&gxw[d];
  const float4 gb = *(const float4*)&gxb[d];
  float o[4];
  {
    float dx = expf(-fmaxf(0.f, Dl.x * gw.x + gb.x));
    o[0] = M.x * X.x + (1.f - M.x) * (dx * Xl.x + (1.f - dx) * xm.x);
  }
  {
    float dx = expf(-fmaxf(0.f, Dl.y * gw.y + gb.y));
    o[1] = M.y * X.y + (1.f - M.y) * (dx * Xl.y + (1.f - dx) * xm.y);
  }
  {
    float dx = expf(-fmaxf(0.f, Dl.z * gw.z + gb.z));
    o[2] = M.z * X.z + (1.f - M.z) * (dx * Xl.z + (1.f - dx) * xm.z);
  }
  {
    float dx = expf(-fmaxf(0.f, Dl.w * gw.w + gb.w));
    o[3] = M.w * X.w + (1.f - M.w) * (dx * Xl.w + (1.f - dx) * xm.w);
  }
  h4_t xo = {(_Float16)o[0], (_Float16)o[1], (_Float16)o[2], (_Float16)o[3]};
  h4_t mo = {(_Float16)M.x, (_Float16)M.y, (_Float16)M.z, (_Float16)M.w};
  h4_t dlo = {(_Float16)Dl.x, (_Float16)Dl.y, (_Float16)Dl.z, (_Float16)Dl.w};
  *(h4_t*)&AH[(size_t)r * 1024 + d] = xo;
  *(h4_t*)&AH[(size_t)r * 1024 + 512 + d] = mo;
  *(h4_t*)&DLh[(size_t)r * 512 + d] = dlo;
}

// ---------------------------------------------------------------------------
// f16 MFMA GEMM: C[M][Ncols] = act(A[M][K] @ BT[Ncols][K]^T + bias)
// 128x128 tile, 256 threads (4 waves, each 64x64 = 4x4 16x16x32 tiles).
// mode 0: C f16, no act. mode 1: C f32, exp(-relu(v)).
// ---------------------------------------------------------------------------
__global__ __launch_bounds__(256, 2) void gemm16(
    const __half* __restrict__ A, const __half* __restrict__ BT,
    const float* __restrict__ bias, void* __restrict__ C,
    int K, int Ncols, int mode) {
  __shared__ _Float16 Ash[128 * 48];
  __shared__ _Float16 Bsh[128 * 48];
  const int tid = threadIdx.x;
  const int lane = tid & 63, w = tid >> 6;
  const int l15 = lane & 15, quad = lane >> 4;
  const int wr = w >> 1, wc = w & 1;
  const int row0 = blockIdx.y * 128, col0 = blockIdx.x * 128;

  f32x4 acc[4][4] = {};

  const int cid0 = tid * 2;
  const int r0 = cid0 >> 2, cc0 = (cid0 & 3) * 8;
  const int r1 = (cid0 + 1) >> 2, cc1 = ((cid0 + 1) & 3) * 8;

  for (int k0 = 0; k0 < K; k0 += 32) {
    h8_t a0 = *(const h8_t*)&A[(size_t)(row0 + r0) * K + k0 + cc0];
    h8_t a1 = *(const h8_t*)&A[(size_t)(row0 + r1) * K + k0 + cc1];
    h8_t b0 = *(const h8_t*)&BT[(size_t)(col0 + r0) * K + k0 + cc0];
    h8_t b1 = *(const h8_t*)&BT[(size_t)(col0 + r1) * K + k0 + cc1];
    __syncthreads();
    *(h8_t*)&Ash[r0 * 48 + cc0] = a0;
    *(h8_t*)&Ash[r1 * 48 + cc1] = a1;
    *(h8_t*)&Bsh[r0 * 48 + cc0] = b0;
    *(h8_t*)&Bsh[r1 * 48 + cc1] = b1;
    __syncthreads();
    h8_t af[4], bf[4];
#pragma unroll
    for (int mt = 0; mt < 4; ++mt)
      af[mt] = *(const h8_t*)&Ash[(wr * 64 + mt * 16 + l15) * 48 + quad * 8];
#pragma unroll
    for (int ct = 0; ct < 4; ++ct)
      bf[ct] = *(const h8_t*)&Bsh[(wc * 64 + ct * 16 + l15) * 48 + quad * 8];
#pragma unroll
    for (int mt = 0; mt < 4; ++mt)
#pragma unroll
      for (int ct = 0; ct < 4; ++ct)
        acc[mt][ct] = __builtin_amdgcn_mfma_f32_16x16x32_f16(af[mt], bf[ct], acc[mt][ct], 0, 0, 0);
  }

#pragma unroll
  for (int ct = 0; ct < 4; ++ct) {
    const int col = col0 + wc * 64 + ct * 16 + l15;
    const float bv = bias[col];
#pragma unroll
    for (int mt = 0; mt < 4; ++mt) {
#pragma unroll
      for (int reg = 0; reg < 4; ++reg) {
        const int row = row0 + wr * 64 + mt * 16 + quad * 4 + reg;
        float v = acc[mt][ct][reg] + bv;
        if (mode == 0) {
          ((__half*)C)[(size_t)row * Ncols + col] = __float2half(v);
        } else {
          ((float*)C)[(size_t)row * Ncols + col] = expf(-fmaxf(0.f, v));
        }
      }
    }
  }
}

// ---------------------------------------------------------------------------
// Recurrence: 32 blocks x 512 threads, cooperative. 4 groups of 8 blocks.
// Group g owns rows [16g,16g+16); member m owns gate cols [256m,256m+256).
// WH in register B-fragments (loaded once). Per step:
//   h staged into LDS in MFMA A-FRAGMENT-LINEAR order (conflict-free b128),
//   MFMA, epilogue, fence-free flag sync (relaxed agent atomics only;
//   ordering via __syncthreads' vmcnt(0) drain -> no wbl2/inv, warm L2).
// ---------------------------------------------------------------------------
__global__ __launch_bounds__(512, 2) void persist_rnn(
    const __half* __restrict__ GPh, const float* __restrict__ DH,
    const __half* __restrict__ WHT, unsigned* __restrict__ hs,
    int* __restrict__ flg, float* __restrict__ out) {
  __shared__ __align__(16) unsigned hlin[4096];  // A-frag-linear h (f16 pairs)
  __shared__ __align__(16) float gbuf[16 * 260];
  const int g = blockIdx.x & 3;   // group
  const int m = blockIdx.x >> 2;  // member 0..7
  const int tid = threadIdx.x;
  const int lane = tid & 63;
  const int w = tid >> 6;
  const int l15 = lane & 15;
  const int quad = lane >> 4;
  const int rowg0 = g << 4;

  // ---- B fragments, loaded once ----
  h8_t bfrag[2][16];
  const int colbase = (m << 8) + (w << 5);
#pragma unroll
  for (int nt = 0; nt < 2; ++nt) {
#pragma unroll
    for (int kt = 0; kt < 16; ++kt) {
      int col = colbase + nt * 16 + l15;
      int k = kt * 32 + quad * 8;
      bfrag[nt][kt] = *(const h8_t*)&WHT[(size_t)col * 512 + k];
    }
  }

  // ---- staging source indices (t-invariant): dest word tid+q*512 ----
  int srcidx[8];
#pragma unroll
  for (int q = 0; q < 8; ++q) {
    int wi = tid + q * 512;
    int kt = wi >> 8, rem = wi & 255;
    int ln = rem >> 2, wj = rem & 3;
    srcidx[q] = (rowg0 + (ln & 15)) * 256 + kt * 16 + (ln >> 4) * 4 + wj;
  }

  float c0 = 0.f, c1 = 0.f;
  const int r_ep = w;
  const int ug = (m << 6) + lane;

  for (int t = 0; t < TT; ++t) {
    // prefetch epilogue operands
    const h4_t gha = *(const h4_t*)&GPh[((size_t)t * 64 + rowg0 + r_ep) * NC + (ug << 2)];
    const h4_t ghb = *(const h4_t*)&GPh[((size_t)t * 64 + rowg0 + r_ep + 8) * NC + (ug << 2)];
    const int tn = (t + 1 < TT) ? t + 1 : t;
    const float dha = DH[((size_t)tn * 64 + rowg0 + r_ep) * HH + ug];
    const float dhb = DH[((size_t)tn * 64 + rowg0 + r_ep + 8) * HH + ug];

    // ---- stage h into LDS (fragment-linear) ----
    const unsigned* hsp = hs + (size_t)(t & 1) * (64 * 256);
#pragma unroll
    for (int q = 0; q < 8; ++q) {
      unsigned v = __hip_atomic_load(&hsp[srcidx[q]], __ATOMIC_RELAXED,
                                     __HIP_MEMORY_SCOPE_AGENT);
      hlin[tid + q * 512] = v;
    }
    __syncthreads();

    // ---- MFMA ----
    f32x4 acc0 = {0.f, 0.f, 0.f, 0.f};
    f32x4 acc1 = {0.f, 0.f, 0.f, 0.f};
    const _Float16* hl16 = (const _Float16*)hlin;
#pragma unroll
    for (int kt = 0; kt < 16; ++kt) {
      h8_t af = *(const h8_t*)&hl16[kt * 512 + lane * 8];
      acc0 = __builtin_amdgcn_mfma_f32_16x16x32_f16(af, bfrag[0][kt], acc0, 0, 0, 0);
      acc1 = __builtin_amdgcn_mfma_f32_16x16x32_f16(af, bfrag[1][kt], acc1, 0, 0, 0);
    }
#pragma unroll
    for (int reg = 0; reg < 4; ++reg) {
      int row = quad * 4 + reg;
      gbuf[row * 260 + (w << 5) + l15] = acc0[reg];
      gbuf[row * 260 + (w << 5) + 16 + l15] = acc1[reg];
    }
    __syncthreads();

    // ---- epilogue: rows r_ep, r_ep+8 ; unit ug ----
    unsigned* hsn = hs + (size_t)((t + 1) & 1) * (64 * 256);
    {
      const float4 gv = *(const float4*)&gbuf[r_ep * 260 + (lane << 2)];
      float ig = sigmoidf_(gv.x + (float)gha[0]);
      float fg = sigmoidf_(gv.y + (float)gha[1]);
      float og = sigmoidf_(gv.z + (float)gha[2]);
      float ct = tanhf(gv.w + (float)gha[3]);
      c0 = fg * c0 + ig * ct;
      float h = og * tanhf(c0);
      out[((size_t)(rowg0 + r_ep) * TT + t) * HH + ug] = h;
      if (t + 1 < TT) {
        unsigned short hb = __half_as_ushort(__float2half(dha * h));
        unsigned other = (unsigned)__shfl_xor((int)(unsigned)hb, 1) & 0xffffu;
        if (!(lane & 1)) {
          unsigned word = (unsigned)hb | (other << 16);
          __hip_atomic_store(&hsn[(size_t)(rowg0 + r_ep) * 256 + (ug >> 1)], word,
                             __ATOMIC_RELAXED, __HIP_MEMORY_SCOPE_AGENT);
        }
      }
    }
    {
      const int r2 = r_ep + 8;
      const float4 gv = *(const float4*)&gbuf[r2 * 260 + (lane << 2)];
      float ig = sigmoidf_(gv.x + (float)ghb[0]);
      float fg = sigmoidf_(gv.y + (float)ghb[1]);
      float og = sigmoidf_(gv.z + (float)ghb[2]);
      float ct = tanhf(gv.w + (float)ghb[3]);
      c1 = fg * c1 + ig * ct;
      float h = og * tanhf(c1);
      out[((size_t)(rowg0 + r2) * TT + t) * HH + ug] = h;
      if (t + 1 < TT) {
        unsigned short hb = __half_as_ushort(__float2half(dhb * h));
        unsigned other = (unsigned)__shfl_xor((int)(unsigned)hb, 1) & 0xffffu;
        if (!(lane & 1)) {
          unsigned word = (unsigned)hb | (other << 16);
          __hip_atomic_store(&hsn[(size_t)(rowg0 + r2) * 256 + (ug >> 1)], word,
                             __ATOMIC_RELAXED, __HIP_MEMORY_SCOPE_AGENT);
        }
      }
    }

    // ---- fence-free flag sync ----
    __syncthreads();  // vmcnt(0) drain: hs stores ack'd at L3 before flag
    if (t + 1 < TT) {
      if (tid == 0)
        __hip_atomic_store(&flg[(g * 8 + m) * 32], t + 1, __ATOMIC_RELAXED,
                           __HIP_MEMORY_SCOPE_AGENT);
      if (tid < 8) {
        while (__hip_atomic_load(&flg[(g * 8 + tid) * 32], __ATOMIC_RELAXED,
                                 __HIP_MEMORY_SCOPE_AGENT) <= t) {
          __builtin_amdgcn_s_sleep(1);
        }
      }
      __atomic_signal_fence(__ATOMIC_SEQ_CST);
      __syncthreads();
    }
  }
}

// ---------------------------------------------------------------------------
extern "C" void kernel_launch(void* const* d_in, const int* in_sizes, int n_in,
                              void* d_out, int out_size, void* d_ws,
                              size_t ws_size, hipStream_t stream) {
  const float* x = (const float*)d_in[0];
  const float* Xmean = (const float*)d_in[1];
  const float* Wi = (const float*)d_in[2];
  const float* bi = (const float*)d_in[3];
  const float* Wf = (const float*)d_in[4];
  const float* bf = (const float*)d_in[5];
  const float* Wo = (const float*)d_in[6];
  const float* bo = (const float*)d_in[7];
  const float* Wc = (const float*)d_in[8];
  const float* bc = (const float*)d_in[9];
  const float* gxw = (const float*)d_in[10];
  const float* gxb = (const float*)d_in[11];
  const float* ghW = (const float*)d_in[12];
  const float* ghb = (const float*)d_in[13];
  float* out = (float*)d_out;
  float* ws = (float*)d_ws;

  __half* AH = (__half*)(ws + AH_OFF);
  __half* DLh = (__half*)(ws + DLH_OFF);
  float* DH = ws + DH_OFF;
  __half* GPh = (__half*)(ws + GP_OFF);
  __half* WCT = (__half*)(ws + WCT_OFF);
  __half* GHT = (__half*)(ws + GHT_OFF);
  __half* WHT = (__half*)(ws + WHT_OFF);
  float* BC = ws + BC_OFF;
  unsigned* HS = (unsigned*)(ws + HS_OFF);
  int* FLG = (int*)(ws + FLG_OFF);

  // zero h exchange buffers + flags (ws poisoned 0xAA each launch)
  hipMemsetAsync(HS, 0, (2ull * 64 * 256 + 1024) * sizeof(unsigned), stream);

  repack_kernel<<<1024, 256, 0, stream>>>(Wi, bi, Wf, bf, Wo, bo, Wc, bc, ghW,
                                          WCT, WHT, GHT, BC);
  xt_kernel<<<8192, 256, 0, stream>>>(x, Xmean, gxw, gxb, AH, DLh);
  // DH = exp(-relu(Dl @ ghW + ghb)) : M=16384, N=512, K=512
  gemm16<<<dim3(4, 128), 256, 0, stream>>>(DLh, GHT, ghb, (void*)DH, 512, 512, 1);
  // GP = [xt|m] @ [Wx;Wm] + BC : M=16384, N=2048, K=1024 (f16 out)
  gemm16<<<dim3(16, 128), 256, 0, stream>>>(AH, WCT, BC, (void*)GPh, 1024, NC, 0);

  void* args[] = {(void*)&GPh, (void*)&DH, (void*)&WHT,
                  (void*)&HS, (void*)&FLG, (void*)&out};
  hipLaunchCooperativeKernel((const void*)persist_rnn, dim3(32), dim3(512),
                             args, 0, stream);
}

// Round 6
// 1407.047 us; speedup vs baseline: 11.3752x; 1.2308x over previous
//
#include <hip/hip_runtime.h>
#include <hip/hip_fp16.h>
#include <math.h>

// Problem dims
#define TT 256
#define BB 64
#define DD 512
#define HH 512
#define NC 2048  // 4 gates * H, col = j*4+g (g: 0=i,1=f,2=o,3=ctilde)

// Workspace layout (float-slot offsets).
#define AH_OFF   0ull          // f16 [16384][1024]  (xt | m), row = t*64+b
#define DLH_OFF  8388608ull    // f16 [16384][512]   Dl
#define DH_OFF   12582912ull   // f32 [16384][512]   delta_h
#define GP_OFF   20971520ull   // f16 [16384][2048]  G_pre
#define WCT_OFF  37748736ull   // f16 [2048][1024]   gate W (x|m), col-major rows
#define GHT_OFF  38797312ull   // f16 [512][512]     gh_W transposed
#define WHT_OFF  38928384ull   // f16 [2048][512]    gate W h-part, col-major rows
#define BC_OFF   39452672ull   // f32 [2048]
#define HS_OFF   39454720ull   // uint [2][4 groups][4096] frag-linear h exchange
#define FLG_OFF  39487488ull   // int [32] flags (4 groups x 8, packed)

typedef _Float16 h8_t __attribute__((ext_vector_type(8)));
typedef _Float16 h4_t __attribute__((ext_vector_type(4)));
typedef float f32x4 __attribute__((ext_vector_type(4)));
typedef unsigned long long ull2_t __attribute__((ext_vector_type(2)));

__device__ __forceinline__ float fast_exp2(float x) {
#if defined(__has_builtin)
#if __has_builtin(__builtin_amdgcn_exp2f)
  return __builtin_amdgcn_exp2f(x);
#else
  return exp2f(x);
#endif
#else
  return exp2f(x);
#endif
}
__device__ __forceinline__ float fast_rcp(float x) {
#if defined(__has_builtin)
#if __has_builtin(__builtin_amdgcn_rcpf)
  return __builtin_amdgcn_rcpf(x);
#else
  return 1.0f / x;
#endif
#else
  return 1.0f / x;
#endif
}
#define LOG2E 1.4426950408889634f
__device__ __forceinline__ float sigmoidf_(float v) {
  return fast_rcp(1.0f + fast_exp2(-LOG2E * v));
}
__device__ __forceinline__ float tanhf_(float v) {
  return 1.0f - 2.0f * fast_rcp(1.0f + fast_exp2(2.0f * LOG2E * v));
}

// ---------------------------------------------------------------------------
// Repack:
//   WCT f16 [2048][1024]: WCT[4j+g][k<512]=Wg[k][j] (x), [512+k]=Wg[1024+k][j] (m)
//   WHT f16 [2048][512] :  WHT[4j+g][k] = Wg[512+k][j]
//   GHT f16 [512][512]  :  GHT[j][k] = ghW[k][j]
//   BC  f32 [2048]
// ---------------------------------------------------------------------------
__global__ __launch_bounds__(256) void repack_kernel(
    const float* __restrict__ Wi, const float* __restrict__ bi,
    const float* __restrict__ Wf, const float* __restrict__ bff,
    const float* __restrict__ Wo, const float* __restrict__ bo,
    const float* __restrict__ Wc, const float* __restrict__ bc,
    const float* __restrict__ ghW,
    __half* __restrict__ WCT, __half* __restrict__ WHT,
    __half* __restrict__ GHT, float* __restrict__ BC) {
  int idx = blockIdx.x * 256 + threadIdx.x;  // 512*512
  int k = idx >> 9, j = idx & 511;
  const float* Ws[4] = {Wi, Wf, Wo, Wc};
  const float* bs[4] = {bi, bff, bo, bc};
#pragma unroll
  for (int g = 0; g < 4; ++g) {
    const float* W = Ws[g];
    int col = j * 4 + g;
    WCT[(size_t)col * 1024 + k] = __float2half(W[(size_t)k * 512 + j]);
    WCT[(size_t)col * 1024 + 512 + k] = __float2half(W[(size_t)(1024 + k) * 512 + j]);
    WHT[(size_t)col * 512 + k] = __float2half(W[(size_t)(512 + k) * 512 + j]);
    if (k == 0) BC[col] = bs[g][j];
  }
  GHT[(size_t)j * 512 + k] = __float2half(ghW[(size_t)k * 512 + j]);
}

// ---------------------------------------------------------------------------
// xt: AH[r][d] = xt (f16), AH[r][512+d] = m (f16), DLh[r][d] = dl (f16)
// x layout: [B][4][T][D]; 0=X,1=Xl,2=M,3=Dl ; r = t*64+b
// ---------------------------------------------------------------------------
__global__ __launch_bounds__(256) void xt_kernel(
    const float* __restrict__ x, const float* __restrict__ Xmean,
    const float* __restrict__ gxw, const float* __restrict__ gxb,
    __half* __restrict__ AH, __half* __restrict__ DLh) {
  int idx = blockIdx.x * 256 + threadIdx.x;
  int d = (idx & 127) * 4;
  int r = idx >> 7;
  int b = r & 63, t = r >> 6;
  size_t base = (((size_t)b * 4) * TT + t) * DD + d;
  const float4 X = *(const float4*)&x[base];
  const float4 Xl = *(const float4*)&x[base + (size_t)TT * DD];
  const float4 M = *(const float4*)&x[base + 2ull * TT * DD];
  const float4 Dl = *(const float4*)&x[base + 3ull * TT * DD];
  const float4 xm = *(const float4*)&Xmean[(size_t)t * DD + d];
  const float4 gw = *(const float4*)&gxw[d];
  const float4 gb = *(const float4*)&gxb[d];
  float o[4];
  {
    float dx = fast_exp2(-LOG2E * fmaxf(0.f, Dl.x * gw.x + gb.x));
    o[0] = M.x * X.x + (1.f - M.x) * (dx * Xl.x + (1.f - dx) * xm.x);
  }
  {
    float dx = fast_exp2(-LOG2E * fmaxf(0.f, Dl.y * gw.y + gb.y));
    o[1] = M.y * X.y + (1.f - M.y) * (dx * Xl.y + (1.f - dx) * xm.y);
  }
  {
    float dx = fast_exp2(-LOG2E * fmaxf(0.f, Dl.z * gw.z + gb.z));
    o[2] = M.z * X.z + (1.f - M.z) * (dx * Xl.z + (1.f - dx) * xm.z);
  }
  {
    float dx = fast_exp2(-LOG2E * fmaxf(0.f, Dl.w * gw.w + gb.w));
    o[3] = M.w * X.w + (1.f - M.w) * (dx * Xl.w + (1.f - dx) * xm.w);
  }
  h4_t xo = {(_Float16)o[0], (_Float16)o[1], (_Float16)o[2], (_Float16)o[3]};
  h4_t mo = {(_Float16)M.x, (_Float16)M.y, (_Float16)M.z, (_Float16)M.w};
  h4_t dlo = {(_Float16)Dl.x, (_Float16)Dl.y, (_Float16)Dl.z, (_Float16)Dl.w};
  *(h4_t*)&AH[(size_t)r * 1024 + d] = xo;
  *(h4_t*)&AH[(size_t)r * 1024 + 512 + d] = mo;
  *(h4_t*)&DLh[(size_t)r * 512 + d] = dlo;
}

// ---------------------------------------------------------------------------
// f16 MFMA GEMM: C[M][Ncols] = act(A[M][K] @ BT[Ncols][K]^T + bias)
// 128x128 tile, 256 threads. mode 0: C f16. mode 1: C f32, exp(-relu(v)).
// ---------------------------------------------------------------------------
__global__ __launch_bounds__(256, 2) void gemm16(
    const __half* __restrict__ A, const __half* __restrict__ BT,
    const float* __restrict__ bias, void* __restrict__ C,
    int K, int Ncols, int mode) {
  __shared__ _Float16 Ash[128 * 48];
  __shared__ _Float16 Bsh[128 * 48];
  const int tid = threadIdx.x;
  const int lane = tid & 63, w = tid >> 6;
  const int l15 = lane & 15, quad = lane >> 4;
  const int wr = w >> 1, wc = w & 1;
  const int row0 = blockIdx.y * 128, col0 = blockIdx.x * 128;

  f32x4 acc[4][4] = {};

  const int cid0 = tid * 2;
  const int r0 = cid0 >> 2, cc0 = (cid0 & 3) * 8;
  const int r1 = (cid0 + 1) >> 2, cc1 = ((cid0 + 1) & 3) * 8;

  for (int k0 = 0; k0 < K; k0 += 32) {
    h8_t a0 = *(const h8_t*)&A[(size_t)(row0 + r0) * K + k0 + cc0];
    h8_t a1 = *(const h8_t*)&A[(size_t)(row0 + r1) * K + k0 + cc1];
    h8_t b0 = *(const h8_t*)&BT[(size_t)(col0 + r0) * K + k0 + cc0];
    h8_t b1 = *(const h8_t*)&BT[(size_t)(col0 + r1) * K + k0 + cc1];
    __syncthreads();
    *(h8_t*)&Ash[r0 * 48 + cc0] = a0;
    *(h8_t*)&Ash[r1 * 48 + cc1] = a1;
    *(h8_t*)&Bsh[r0 * 48 + cc0] = b0;
    *(h8_t*)&Bsh[r1 * 48 + cc1] = b1;
    __syncthreads();
    h8_t af[4], bf[4];
#pragma unroll
    for (int mt = 0; mt < 4; ++mt)
      af[mt] = *(const h8_t*)&Ash[(wr * 64 + mt * 16 + l15) * 48 + quad * 8];
#pragma unroll
    for (int ct = 0; ct < 4; ++ct)
      bf[ct] = *(const h8_t*)&Bsh[(wc * 64 + ct * 16 + l15) * 48 + quad * 8];
#pragma unroll
    for (int mt = 0; mt < 4; ++mt)
#pragma unroll
      for (int ct = 0; ct < 4; ++ct)
        acc[mt][ct] = __builtin_amdgcn_mfma_f32_16x16x32_f16(af[mt], bf[ct], acc[mt][ct], 0, 0, 0);
  }

#pragma unroll
  for (int ct = 0; ct < 4; ++ct) {
    const int col = col0 + wc * 64 + ct * 16 + l15;
    const float bv = bias[col];
#pragma unroll
    for (int mt = 0; mt < 4; ++mt) {
#pragma unroll
      for (int reg = 0; reg < 4; ++reg) {
        const int row = row0 + wr * 64 + mt * 16 + quad * 4 + reg;
        float v = acc[mt][ct][reg] + bv;
        if (mode == 0) {
          ((__half*)C)[(size_t)row * Ncols + col] = __float2half(v);
        } else {
          ((float*)C)[(size_t)row * Ncols + col] = fast_exp2(-LOG2E * fmaxf(0.f, v));
        }
      }
    }
  }
}

// ---------------------------------------------------------------------------
// Recurrence: 32 blocks x 512 threads, cooperative. 4 groups of 8 blocks.
// Group g owns rows [16g,16g+16); member m owns gate cols [256m,256m+256).
// WH in register B-fragments. h exchange buffer is stored in global memory in
// MFMA A-FRAGMENT-LINEAR order (per group): uint idx = kt*256 + lane*4 + q
// holds (row=lane&15, k=kt*32+(lane>>4)*8+2q+{0,1}). Waves load A-frags
// straight from L3 (agent-scope 8-B atomic loads, 1 KB/instr coalescing) —
// NO LDS staging. Sync: 2 __syncthreads/step + per-wave flag poll (all lanes
// read the group's 8 packed flags); flag set after the vm-drain barrier, so
// own-flag >= t+1 implies all of that block's reads/stores for step t done.
// ---------------------------------------------------------------------------
__global__ __launch_bounds__(512, 2) void persist_rnn(
    const __half* __restrict__ GPh, const float* __restrict__ DH,
    const __half* __restrict__ WHT, unsigned* __restrict__ hs,
    int* __restrict__ flg, float* __restrict__ out) {
  __shared__ __align__(16) float gbuf[16 * 260];
  const int g = blockIdx.x & 3;   // group
  const int m = blockIdx.x >> 2;  // member 0..7
  const int tid = threadIdx.x;
  const int lane = tid & 63;
  const int w = tid >> 6;
  const int l15 = lane & 15;
  const int quad = lane >> 4;
  const int rowg0 = g << 4;

  // ---- B fragments, loaded once ----
  h8_t bfrag[2][16];
  const int colbase = (m << 8) + (w << 5);
#pragma unroll
  for (int nt = 0; nt < 2; ++nt) {
#pragma unroll
    for (int kt = 0; kt < 16; ++kt) {
      int col = colbase + nt * 16 + l15;
      int k = kt * 32 + quad * 8;
      bfrag[nt][kt] = *(const h8_t*)&WHT[(size_t)col * 512 + k];
    }
  }

  const int r_ep = w;
  const int ug = (m << 6) + lane;
  // frag-layout dest uint indices for the two h stores (even lanes use them)
  const int ktu = ug >> 5, q3 = (ug >> 3) & 3, qi = (ug & 7) >> 1;
  const int d0 = ktu * 256 + (q3 * 16 + r_ep) * 4 + qi;
  const int d1 = ktu * 256 + (q3 * 16 + r_ep + 8) * 4 + qi;

  float c0 = 0.f, c1 = 0.f;

  for (int t = 0; t < TT; ++t) {
    // ---- per-wave poll: wait until all 8 group flags >= t ----
    if (t > 0) {
      const int* fb = flg + (g << 3);
      for (;;) {
        int v = __hip_atomic_load(&fb[lane & 7], __ATOMIC_RELAXED,
                                  __HIP_MEMORY_SCOPE_AGENT);
        if (__all(v >= t)) break;
        __builtin_amdgcn_s_sleep(1);
      }
    }

    // ---- epilogue operand streams (HBM; hidden behind MFMA phase) ----
    const h4_t gha = *(const h4_t*)&GPh[((size_t)t * 64 + rowg0 + r_ep) * NC + (ug << 2)];
    const h4_t ghb = *(const h4_t*)&GPh[((size_t)t * 64 + rowg0 + r_ep + 8) * NC + (ug << 2)];
    const int tn = (t + 1 < TT) ? t + 1 : t;
    const float dha = DH[((size_t)tn * 64 + rowg0 + r_ep) * HH + ug];
    const float dhb = DH[((size_t)tn * 64 + rowg0 + r_ep + 8) * HH + ug];

    // ---- A fragments straight from L3 (frag-linear layout) ----
    const unsigned long long* hsp =
        (const unsigned long long*)hs + ((size_t)(t & 1) * 4 + g) * 2048;
    h8_t af[16];
#pragma unroll
    for (int kt = 0; kt < 16; ++kt) {
      unsigned long long a = __hip_atomic_load(&hsp[kt * 128 + lane * 2],
                                               __ATOMIC_RELAXED,
                                               __HIP_MEMORY_SCOPE_AGENT);
      unsigned long long b = __hip_atomic_load(&hsp[kt * 128 + lane * 2 + 1],
                                               __ATOMIC_RELAXED,
                                               __HIP_MEMORY_SCOPE_AGENT);
      ull2_t u2 = {a, b};
      af[kt] = __builtin_bit_cast(h8_t, u2);
    }

    // ---- MFMA ----
    f32x4 acc0 = {0.f, 0.f, 0.f, 0.f};
    f32x4 acc1 = {0.f, 0.f, 0.f, 0.f};
#pragma unroll
    for (int kt = 0; kt < 16; ++kt) {
      acc0 = __builtin_amdgcn_mfma_f32_16x16x32_f16(af[kt], bfrag[0][kt], acc0, 0, 0, 0);
      acc1 = __builtin_amdgcn_mfma_f32_16x16x32_f16(af[kt], bfrag[1][kt], acc1, 0, 0, 0);
    }
#pragma unroll
    for (int reg = 0; reg < 4; ++reg) {
      int row = quad * 4 + reg;
      gbuf[row * 260 + (w << 5) + l15] = acc0[reg];
      gbuf[row * 260 + (w << 5) + 16 + l15] = acc1[reg];
    }
    __syncthreads();

    // ---- epilogue: rows r_ep, r_ep+8 ; unit ug ----
    unsigned* hsn = hs + ((size_t)((t + 1) & 1) * 4 + g) * 4096;
    {
      const float4 gv = *(const float4*)&gbuf[r_ep * 260 + (lane << 2)];
      float ig = sigmoidf_(gv.x + (float)gha[0]);
      float fg = sigmoidf_(gv.y + (float)gha[1]);
      float og = sigmoidf_(gv.z + (float)gha[2]);
      float ct = tanhf_(gv.w + (float)gha[3]);
      c0 = fg * c0 + ig * ct;
      float h = og * tanhf_(c0);
      out[((size_t)(rowg0 + r_ep) * TT + t) * HH + ug] = h;
      if (t + 1 < TT) {
        unsigned short hb = __half_as_ushort(__float2half(dha * h));
        unsigned other = (unsigned)__shfl_xor((int)(unsigned)hb, 1) & 0xffffu;
        if (!(lane & 1)) {
          unsigned word = (unsigned)hb | (other << 16);
          __hip_atomic_store(&hsn[d0], word, __ATOMIC_RELAXED,
                             __HIP_MEMORY_SCOPE_AGENT);
        }
      }
    }
    {
      const float4 gv = *(const float4*)&gbuf[(r_ep + 8) * 260 + (lane << 2)];
      float ig = sigmoidf_(gv.x + (float)ghb[0]);
      float fg = sigmoidf_(gv.y + (float)ghb[1]);
      float og = sigmoidf_(gv.z + (float)ghb[2]);
      float ct = tanhf_(gv.w + (float)ghb[3]);
      c1 = fg * c1 + ig * ct;
      float h = og * tanhf_(c1);
      out[((size_t)(rowg0 + r_ep + 8) * TT + t) * HH + ug] = h;
      if (t + 1 < TT) {
        unsigned short hb = __half_as_ushort(__float2half(dhb * h));
        unsigned other = (unsigned)__shfl_xor((int)(unsigned)hb, 1) & 0xffffu;
        if (!(lane & 1)) {
          unsigned word = (unsigned)hb | (other << 16);
          __hip_atomic_store(&hsn[d1], word, __ATOMIC_RELAXED,
                             __HIP_MEMORY_SCOPE_AGENT);
        }
      }
    }

    // ---- vm-drain barrier, then publish flag ----
    __syncthreads();  // compiler emits s_waitcnt vmcnt(0) per wave before barrier
    if (t + 1 < TT && tid == 0)
      __hip_atomic_store(&flg[(g << 3) + m], t + 1, __ATOMIC_RELAXED,
                         __HIP_MEMORY_SCOPE_AGENT);
  }
}

// ---------------------------------------------------------------------------
extern "C" void kernel_launch(void* const* d_in, const int* in_sizes, int n_in,
                              void* d_out, int out_size, void* d_ws,
                              size_t ws_size, hipStream_t stream) {
  const float* x = (const float*)d_in[0];
  const float* Xmean = (const float*)d_in[1];
  const float* Wi = (const float*)d_in[2];
  const float* bi = (const float*)d_in[3];
  const float* Wf = (const float*)d_in[4];
  const float* bf = (const float*)d_in[5];
  const float* Wo = (const float*)d_in[6];
  const float* bo = (const float*)d_in[7];
  const float* Wc = (const float*)d_in[8];
  const float* bc = (const float*)d_in[9];
  const float* gxw = (const float*)d_in[10];
  const float* gxb = (const float*)d_in[11];
  const float* ghW = (const float*)d_in[12];
  const float* ghb = (const float*)d_in[13];
  float* out = (float*)d_out;
  float* ws = (float*)d_ws;

  __half* AH = (__half*)(ws + AH_OFF);
  __half* DLh = (__half*)(ws + DLH_OFF);
  float* DH = ws + DH_OFF;
  __half* GPh = (__half*)(ws + GP_OFF);
  __half* WCT = (__half*)(ws + WCT_OFF);
  __half* GHT = (__half*)(ws + GHT_OFF);
  __half* WHT = (__half*)(ws + WHT_OFF);
  float* BC = ws + BC_OFF;
  unsigned* HS = (unsigned*)(ws + HS_OFF);
  int* FLG = (int*)(ws + FLG_OFF);

  // zero h exchange buffers + flags (ws poisoned 0xAA each launch)
  hipMemsetAsync(HS, 0, (2ull * 4 * 4096 + 64) * sizeof(unsigned), stream);

  repack_kernel<<<1024, 256, 0, stream>>>(Wi, bi, Wf, bf, Wo, bo, Wc, bc, ghW,
                                          WCT, WHT, GHT, BC);
  xt_kernel<<<8192, 256, 0, stream>>>(x, Xmean, gxw, gxb, AH, DLh);
  // DH = exp(-relu(Dl @ ghW + ghb)) : M=16384, N=512, K=512
  gemm16<<<dim3(4, 128), 256, 0, stream>>>(DLh, GHT, ghb, (void*)DH, 512, 512, 1);
  // GP = [xt|m] @ [Wx;Wm] + BC : M=16384, N=2048, K=1024 (f16 out)
  gemm16<<<dim3(16, 128), 256, 0, stream>>>(AH, WCT, BC, (void*)GPh, 1024, NC, 0);

  void* args[] = {(void*)&GPh, (void*)&DH, (void*)&WHT,
                  (void*)&HS, (void*)&FLG, (void*)&out};
  hipLaunchCooperativeKernel((const void*)persist_rnn, dim3(32), dim3(512),
                             args, 0, stream);
}